// Round 8
// baseline (232.165 us; speedup 1.0000x reference)
//
#include <hip/hip_runtime.h>
#include <stdint.h>

#define BN 4
#define CD 256
#define ND 4096
#define NK 32            // key-tile size in attention

typedef unsigned short u16;
typedef short bfrag __attribute__((ext_vector_type(8)));  // 8 bf16 = 4 VGPR
typedef float ffrag __attribute__((ext_vector_type(4)));  // MFMA C/D frag

__device__ __forceinline__ float bf2f(u16 u) {
  union { unsigned int i; float f; } v;
  v.i = ((unsigned int)u) << 16;
  return v.f;
}
__device__ __forceinline__ u16 f2bf(float f) {
  union { float f; unsigned int i; } v;
  v.f = f;
  return (u16)((v.i + 0x7FFFu + ((v.i >> 16) & 1u)) >> 16);  // RNE
}
// async global->LDS DMA, 16B per lane; LDS dest = wave-uniform base + lane*16
__device__ __forceinline__ void gload_lds(const u16* g, u16* l) {
  __builtin_amdgcn_global_load_lds(
      (const __attribute__((address_space(1))) void*)g,
      (__attribute__((address_space(3))) void*)l, 16, 0, 0);
}

// ---------- convert fp32 weights [256][256] x3 -> bf16 ----------
__global__ __launch_bounds__(256) void k_cvtW(
    const float* __restrict__ Wq, const float* __restrict__ Wk,
    const float* __restrict__ Wv, u16* __restrict__ wb) {
  int m = blockIdx.y;
  const float* src = (m == 0) ? Wq : ((m == 1) ? Wk : Wv);
  u16* dst = wb + (size_t)m * CD * CD;
  int i = (blockIdx.x * 256 + threadIdx.x) * 4;
  float4 v = *(const float4*)(src + i);
  ushort4 o;
  o.x = f2bf(v.x); o.y = f2bf(v.y); o.z = f2bf(v.z); o.w = f2bf(v.w);
  *(ushort4*)(dst + i) = o;
}

// ---------- Q/K projection: one block = 64 rows x all 256 d ----------
// grid (256, 2): x = m-tile, z(y-dim) = 0:Q,1:K.
// Input tile transposed+cast to LDS ONCE; weight frags read direct from
// global bf16 (L2-hot 128 KB), B-operand layout = 8 contiguous bf16.
__global__ __launch_bounds__(256, 2) void k_projQK(
    const float* __restrict__ x, const float* __restrict__ y,
    const u16* __restrict__ wB, const float* __restrict__ bq,
    const float* __restrict__ bk, u16* __restrict__ Qb, u16* __restrict__ Kb) {
  __shared__ alignas(16) u16 As[64][264];  // As[n][c], input^T cast
  int m0 = blockIdx.x * 64;  // global row in [0,16384)
  int z = blockIdx.y;
  int b = m0 >> 12, nsp = m0 & 4095;
  const float* src = (z ? y : x) + (size_t)b * CD * ND;
  const u16* Wsrc = wB + (size_t)z * CD * CD;  // bf16 [d][c]
  const float* bias = z ? bk : bq;
  u16* Cd = (z ? Kb : Qb) + (size_t)m0 * CD;
  int t = threadIdx.x, w = t >> 6, l = t & 63;
  int lane16 = l & 15, quad = l >> 4;

  // A: As[nl][c] = src[c][nsp+nl], all 256 c (transpose+cast in LDS)
#pragma unroll
  for (int it = 0; it < 16; ++it) {
    int idx = it * 256 + t;
    int c = idx >> 4, nj = (idx & 15) * 4;
    float4 v = *(const float4*)(src + (size_t)c * ND + nsp + nj);
    As[nj + 0][c] = f2bf(v.x);
    As[nj + 1][c] = f2bf(v.y);
    As[nj + 2][c] = f2bf(v.z);
    As[nj + 3][c] = f2bf(v.w);
  }
  __syncthreads();

  // A-frags held in registers (rows w*16+lane16, 8 kc chunks)
  bfrag af[8];
#pragma unroll
  for (int kc = 0; kc < 8; ++kc)
    af[kc] = *(const bfrag*)&As[w * 16 + lane16][kc * 32 + quad * 8];

  ffrag acc[16];  // [n0t*4 + tt]
#pragma unroll
  for (int i = 0; i < 16; ++i) acc[i] = ffrag{0.f, 0.f, 0.f, 0.f};
#pragma unroll
  for (int kc = 0; kc < 8; ++kc) {
#pragma unroll
    for (int nt = 0; nt < 16; ++nt) {  // 16 d-tiles of 16
      bfrag bfr = *(const bfrag*)(Wsrc + (size_t)(nt * 16 + lane16) * CD +
                                  kc * 32 + quad * 8);
      acc[nt] = __builtin_amdgcn_mfma_f32_16x16x32_bf16(af[kc], bfr, acc[nt], 0, 0, 0);
    }
  }
  // epilogue: row = w*16+quad*4+r, col = nt*16+lane16
#pragma unroll
  for (int nt = 0; nt < 16; ++nt) {
    int col = nt * 16 + lane16;
    float bcol = bias[col];
#pragma unroll
    for (int r = 0; r < 4; ++r) {
      int rowL = w * 16 + quad * 4 + r;
      Cd[(size_t)rowL * CD + col] = f2bf(acc[nt][r] + bcol);
    }
  }
}

// ---------- V projection: one block = 64 n x all 256 d, out Vt[b][d][n] ----
// grid (64, 4): x = n-tile, z(y-dim) = b. y^T tile staged ONCE; Wv frags
// direct from global bf16 in A-operand layout.
__global__ __launch_bounds__(256, 2) void k_projV(
    const float* __restrict__ y, const u16* __restrict__ WvB,
    const float* __restrict__ bv, u16* __restrict__ Vb) {
  __shared__ alignas(16) u16 Bs[64][264];  // Bs[n][c] = y^T cast
  int n0s = blockIdx.x * 64;
  int b = blockIdx.y;
  const float* src = y + (size_t)b * CD * ND;
  u16* Cd = Vb + (size_t)b * CD * ND;
  int t = threadIdx.x, w = t >> 6, l = t & 63;
  int lane16 = l & 15, quad = l >> 4;

  // stage Bs[nl][c] = src[c][n0s+nl], all 256 c
#pragma unroll
  for (int it = 0; it < 16; ++it) {
    int idx = it * 256 + t;
    int c = idx >> 4, nj = (idx & 15) * 4;
    float4 v = *(const float4*)(src + (size_t)c * ND + n0s + nj);
    Bs[nj + 0][c] = f2bf(v.x);
    Bs[nj + 1][c] = f2bf(v.y);
    Bs[nj + 2][c] = f2bf(v.z);
    Bs[nj + 3][c] = f2bf(v.w);
  }
  __syncthreads();

  // B-frags held in registers (n rows w*16+lane16)
  bfrag bfr[8];
#pragma unroll
  for (int kc = 0; kc < 8; ++kc)
    bfr[kc] = *(const bfrag*)&Bs[w * 16 + lane16][kc * 32 + quad * 8];

  ffrag o[16];  // 16 d-tiles (m)
#pragma unroll
  for (int i = 0; i < 16; ++i) o[i] = ffrag{0.f, 0.f, 0.f, 0.f};
#pragma unroll
  for (int kc = 0; kc < 8; ++kc) {
#pragma unroll
    for (int mt = 0; mt < 16; ++mt) {
      bfrag af = *(const bfrag*)(WvB + (size_t)(mt * 16 + lane16) * CD +
                                 kc * 32 + quad * 8);
      o[mt] = __builtin_amdgcn_mfma_f32_16x16x32_bf16(af, bfr[kc], o[mt], 0, 0, 0);
    }
  }
  // epilogue: d = mt*16+quad*4+r, n = n0s + w*16 + lane16
#pragma unroll
  for (int mt = 0; mt < 16; ++mt) {
#pragma unroll
    for (int r = 0; r < 4; ++r) {
      int d = mt * 16 + quad * 4 + r;
      Cd[(size_t)d * ND + n0s + w * 16 + lane16] = f2bf(o[mt][r] + bv[d]);
    }
  }
}

// ---------- flash attention, split-K, async-DMA double-buffered ----------
// Q,K: [B*N][C]; Vt: [B][C][N]. 128 q-rows/block, 4 waves x 2 m-tiles.
// One __syncthreads per K-tile. XOR-swizzled unpadded LDS (global_load_lds).
union SmemU {
  struct {
    u16 Ks[2][NK][256];   // 32,768 B  chunk^=(row&7) swizzle
    u16 Vs[2][CD][NK];    // 32,768 B  chunk^=((d>>1)&3) swizzle
    u16 Ps[8][16][40];    // 10,240 B  wave-private P staging
  } a;                     // 75,776 B
  u16 ot[CD][136];         // 69,632 B  epilogue O^T staging
};

template <int NS>
__global__ __launch_bounds__(256, 2) void k_attn(
    const u16* __restrict__ Q, const u16* __restrict__ K,
    const u16* __restrict__ Vt, u16* __restrict__ O01,
    u16* __restrict__ O23, float* __restrict__ Lpart) {
  constexpr int NIT = ND / NS / NK;
  __shared__ alignas(16) SmemU sm;
  int b = blockIdx.y, q0 = blockIdx.x * 128, z = blockIdx.z;
  int t = threadIdx.x, w = t >> 6, l = t & 63;
  int lane16 = l & 15, quad = l >> 4;
  const float scale = 0.0625f;  // 256^-0.5

  // Q frags: A-layout rows q0 + (w*2+mi)*16 + lane16
  bfrag qf[2][8];
#pragma unroll
  for (int mi = 0; mi < 2; ++mi) {
    const u16* Qrow =
        Q + ((size_t)b * ND + q0 + (w * 2 + mi) * 16 + lane16) * CD;
#pragma unroll
    for (int kc = 0; kc < 8; ++kc)
      qf[mi][kc] = *(const bfrag*)(Qrow + kc * 32 + quad * 8);
  }

  ffrag o[2][16];
#pragma unroll
  for (int mi = 0; mi < 2; ++mi)
#pragma unroll
    for (int i = 0; i < 16; ++i) o[mi][i] = ffrag{0.f, 0.f, 0.f, 0.f};
  float lsum[2][4] = {{0.f, 0.f, 0.f, 0.f}, {0.f, 0.f, 0.f, 0.f}};

  const u16* Kb = K + ((size_t)b * ND + z * (ND / NS)) * CD;
  const u16* Vb = Vt + (size_t)b * CD * ND + z * (ND / NS);

  auto stage = [&](int kt2) {
    int dbuf = kt2 & 1;
    const u16* Kt = Kb + (size_t)kt2 * NK * CD;
    const u16* Vtt = Vb + kt2 * NK;
#pragma unroll
    for (int p = 0; p < 4; ++p) {
      int r = p * 8 + w * 2 + (l >> 5);
      int j = (l & 31) ^ (r & 7);
      gload_lds(Kt + (size_t)r * CD + j * 8, &sm.a.Ks[dbuf][p * 8 + w * 2][0]);
    }
#pragma unroll
    for (int p = 0; p < 4; ++p) {
      int dd = p * 64 + w * 16 + (l >> 2);
      int j = (l & 3) ^ ((dd >> 1) & 3);
      gload_lds(Vtt + (size_t)dd * ND + j * 8, &sm.a.Vs[dbuf][p * 64 + w * 16][0]);
    }
  };

  stage(0);
  for (int kt = 0; kt < NIT; ++kt) {
    int dbuf = kt & 1;
    __syncthreads();  // drains DMA for buf dbuf; recycling of dbuf^1 is safe
    if (kt + 1 < NIT) stage(kt + 1);  // async into other buffer, no wait

    // S = Q K^T  (2 m-tiles x 2 key-tiles)
    ffrag s2[2][2];
#pragma unroll
    for (int mi = 0; mi < 2; ++mi)
#pragma unroll
      for (int tt = 0; tt < 2; ++tt) s2[mi][tt] = ffrag{0.f, 0.f, 0.f, 0.f};
#pragma unroll
    for (int kc = 0; kc < 8; ++kc) {
      bfrag kf0, kf1;
      {
        int r = lane16;
        int cp = (kc * 4 + quad) ^ (r & 7);
        kf0 = *(const bfrag*)&sm.a.Ks[dbuf][r][cp * 8];
        int r1 = 16 + lane16;
        int cp1 = (kc * 4 + quad) ^ (r1 & 7);
        kf1 = *(const bfrag*)&sm.a.Ks[dbuf][r1][cp1 * 8];
      }
#pragma unroll
      for (int mi = 0; mi < 2; ++mi) {
        s2[mi][0] = __builtin_amdgcn_mfma_f32_16x16x32_bf16(qf[mi][kc], kf0,
                                                            s2[mi][0], 0, 0, 0);
        s2[mi][1] = __builtin_amdgcn_mfma_f32_16x16x32_bf16(qf[mi][kc], kf1,
                                                            s2[mi][1], 0, 0, 0);
      }
    }

    // fixed-max softmax: p = exp(s*scale); lane-partial sums; P -> LDS
#pragma unroll
    for (int mi = 0; mi < 2; ++mi)
#pragma unroll
      for (int tt = 0; tt < 2; ++tt)
#pragma unroll
        for (int r = 0; r < 4; ++r) {
          float p = __expf(s2[mi][tt][r] * scale);
          lsum[mi][r] += p;
          sm.a.Ps[w * 2 + mi][quad * 4 + r][tt * 16 + lane16] = f2bf(p);
        }
    // wave-private Ps: in-wave LDS ordering suffices, no barrier
    bfrag pf0 = *(const bfrag*)&sm.a.Ps[w * 2 + 0][lane16][quad * 8];
    bfrag pf1 = *(const bfrag*)&sm.a.Ps[w * 2 + 1][lane16][quad * 8];

    // O += P V  (16 d-tiles, V-frag shared across both m-tiles)
#pragma unroll
    for (int dt = 0; dt < 16; ++dt) {
      int dd = dt * 16 + lane16;
      int cp = quad ^ ((dd >> 1) & 3);
      bfrag vf = *(const bfrag*)&sm.a.Vs[dbuf][dd][cp * 8];
      o[0][dt] = __builtin_amdgcn_mfma_f32_16x16x32_bf16(pf0, vf, o[0][dt], 0, 0, 0);
      o[1][dt] = __builtin_amdgcn_mfma_f32_16x16x32_bf16(pf1, vf, o[1][dt], 0, 0, 0);
    }
  }

  // row-sum reduction: 16-lane butterfly within quad groups, once
#pragma unroll
  for (int mi = 0; mi < 2; ++mi)
#pragma unroll
    for (int r = 0; r < 4; ++r) {
#pragma unroll
      for (int off = 1; off < 16; off <<= 1)
        lsum[mi][r] += __shfl_xor(lsum[mi][r], off, 64);
    }
  if (lane16 == 0) {
#pragma unroll
    for (int mi = 0; mi < 2; ++mi)
#pragma unroll
      for (int r = 0; r < 4; ++r)
        Lpart[((size_t)z * BN + b) * ND + q0 + (w * 2 + mi) * 16 + quad * 4 + r] =
            lsum[mi][r];
  }

  __syncthreads();
  // unnormalized O -> transposed bf16 staging ot[d][q_local]
#pragma unroll
  for (int mi = 0; mi < 2; ++mi)
#pragma unroll
    for (int dt = 0; dt < 16; ++dt)
#pragma unroll
      for (int r = 0; r < 4; ++r)
        sm.ot[dt * 16 + lane16][(w * 2 + mi) * 16 + quad * 4 + r] =
            f2bf(o[mi][dt][r]);
  __syncthreads();
  const size_t SZc = (size_t)BN * ND * CD;
  u16* Op = ((z < 2) ? O01 : O23) + (size_t)(z & 1) * SZc;
#pragma unroll
  for (int it = 0; it < 16; ++it) {
    int c = it * 256 + t;
    int dd = c >> 4, co = (c & 15) * 8;
    size_t g = ((size_t)b * CD + dd) * ND + q0 + co;
    *(uint4*)(Op + g) = *(const uint4*)&sm.ot[dd][co];
  }
}

// ---------- combine partials + residual ----------
template <int NS>
__global__ __launch_bounds__(256) void k_combine(
    const u16* __restrict__ O01, const u16* __restrict__ O23,
    const float* __restrict__ L, const float* __restrict__ x,
    float* __restrict__ out) {
  const size_t SZc = (size_t)BN * ND * CD;
  size_t e = ((size_t)blockIdx.x * 256 + threadIdx.x) * 8;
  int n = (int)(e & (ND - 1));
  int b = (int)(e >> 20);  // C*N = 2^20
  float ls[8] = {0, 0, 0, 0, 0, 0, 0, 0};
  float acc[8] = {0, 0, 0, 0, 0, 0, 0, 0};
#pragma unroll
  for (int z = 0; z < NS; ++z) {
    const float* Lr = L + ((size_t)z * BN + b) * ND + n;
    float4 l0 = *(const float4*)(Lr);
    float4 l1 = *(const float4*)(Lr + 4);
    ls[0] += l0.x; ls[1] += l0.y; ls[2] += l0.z; ls[3] += l0.w;
    ls[4] += l1.x; ls[5] += l1.y; ls[6] += l1.z; ls[7] += l1.w;
    const u16* Oz = ((z < 2) ? O01 : O23) + (size_t)(z & 1) * SZc + e;
    union { uint4 q; u16 s[8]; } u;
    u.q = *(const uint4*)Oz;
#pragma unroll
    for (int j = 0; j < 8; ++j) acc[j] += bf2f(u.s[j]);
  }
  float4 x0 = *(const float4*)(x + e);
  float4 x1 = *(const float4*)(x + e + 4);
  float4 r0, r1;
  r0.x = x0.x + acc[0] / ls[0];
  r0.y = x0.y + acc[1] / ls[1];
  r0.z = x0.z + acc[2] / ls[2];
  r0.w = x0.w + acc[3] / ls[3];
  r1.x = x1.x + acc[4] / ls[4];
  r1.y = x1.y + acc[5] / ls[5];
  r1.z = x1.z + acc[6] / ls[6];
  r1.w = x1.w + acc[7] / ls[7];
  *(float4*)(out + e) = r0;
  *(float4*)(out + e + 4) = r1;
}

extern "C" void kernel_launch(void* const* d_in, const int* in_sizes, int n_in,
                              void* d_out, int out_size, void* d_ws, size_t ws_size,
                              hipStream_t stream) {
  const float* x  = (const float*)d_in[0];
  const float* y  = (const float*)d_in[1];
  const float* Wq = (const float*)d_in[2];
  const float* bq = (const float*)d_in[3];
  const float* Wk = (const float*)d_in[4];
  const float* bk = (const float*)d_in[5];
  const float* Wv = (const float*)d_in[6];
  const float* bv = (const float*)d_in[7];
  float* out = (float*)d_out;
  u16* ws = (u16*)d_ws;
  const size_t SZ = (size_t)BN * ND * CD;  // 4,194,304 elems per tensor
  u16* Qb = ws;
  u16* Kb = Qb + SZ;
  u16* Vb = Kb + SZ;
  u16* Ob = Vb + SZ;   // NS partials, contiguous
  u16* wB = Ob;        // bf16 weights overlay Ob (dead until k_attn writes it)
  // NS=4 needs: 7*SZ bf16 + 4*BN*ND fp32 = 58.7 MB + 256 KB
  const size_t need4 = 7 * SZ * sizeof(u16) + (size_t)4 * BN * ND * sizeof(float);
  const bool big = ws_size >= need4;  // constant across calls (graph-safe)
  const int cgrid = (int)(SZ / (256 * 8));  // 2048 blocks (out = SZ floats)

  k_cvtW<<<dim3(64, 3), 256, 0, stream>>>(Wq, Wk, Wv, wB);
  k_projQK<<<dim3(256, 2), 256, 0, stream>>>(x, y, wB, bq, bk, Qb, Kb);
  k_projV<<<dim3(64, 4), 256, 0, stream>>>(y, wB + (size_t)2 * CD * CD, bv, Vb);
  if (big) {
    float* Lp = (float*)(Ob + 4 * SZ);
    k_attn<4><<<dim3(ND / 128, BN, 4), 256, 0, stream>>>(Qb, Kb, Vb, Ob,
                                                         Ob + 2 * SZ, Lp);
    k_combine<4><<<dim3(cgrid), 256, 0, stream>>>(Ob, Ob + 2 * SZ, Lp, x, out);
  } else {
    float* Lp = (float*)(Ob + 2 * SZ);
    k_attn<2><<<dim3(ND / 128, BN, 2), 256, 0, stream>>>(Qb, Kb, Vb, Ob, Ob, Lp);
    k_combine<2><<<dim3(cgrid), 256, 0, stream>>>(Ob, Ob, Lp, x, out);
  }
}

// Round 9
// 206.879 us; speedup vs baseline: 1.1222x; 1.1222x over previous
//
#include <hip/hip_runtime.h>
#include <stdint.h>

#define BN 4
#define CD 256
#define ND 4096
#define NK 32            // key-tile size in attention

typedef unsigned short u16;
typedef short bfrag __attribute__((ext_vector_type(8)));  // 8 bf16 = 4 VGPR
typedef float ffrag __attribute__((ext_vector_type(4)));  // MFMA C/D frag

__device__ __forceinline__ float bf2f(u16 u) {
  union { unsigned int i; float f; } v;
  v.i = ((unsigned int)u) << 16;
  return v.f;
}
__device__ __forceinline__ u16 f2bf(float f) {
  union { float f; unsigned int i; } v;
  v.f = f;
  return (u16)((v.i + 0x7FFFu + ((v.i >> 16) & 1u)) >> 16);  // RNE
}
// async global->LDS DMA, 16B per lane; LDS dest = wave-uniform base + lane*16
__device__ __forceinline__ void gload_lds(const u16* g, u16* l) {
  __builtin_amdgcn_global_load_lds(
      (const __attribute__((address_space(1))) void*)g,
      (__attribute__((address_space(3))) void*)l, 16, 0, 0);
}

// ---------- transpose+cast [B][C][N] fp32 -> [B][N][C] bf16 ----------
// grid (64, 4, 9): bz<4: x, bz<8: y; bz==8: weight fp32->bf16 conversion
__global__ __launch_bounds__(256) void k_transpose(
    const float* __restrict__ x, const float* __restrict__ y,
    const float* __restrict__ Wq, const float* __restrict__ Wk,
    const float* __restrict__ Wv, u16* __restrict__ xT,
    u16* __restrict__ yT, u16* __restrict__ wB) {
  int bz = blockIdx.z;
  int t = threadIdx.x;
  if (bz == 8) {
    // weight conversion: 3 x 65536 floats; 192 active blocks x 1024 floats
    int idx = blockIdx.y * 64 + blockIdx.x;
    if (idx < 192) {
      int m = idx >> 6;                 // matrix 0..2
      int off = (idx & 63) * 1024 + t * 4;
      const float* src = (m == 0) ? Wq : ((m == 1) ? Wk : Wv);
      float4 v = *(const float4*)(src + off);
      ushort4 o;
      o.x = f2bf(v.x); o.y = f2bf(v.y); o.z = f2bf(v.z); o.w = f2bf(v.w);
      *(ushort4*)(wB + (size_t)m * CD * CD + off) = o;
    }
    return;
  }
  __shared__ alignas(16) u16 tile[64][72];
  int n0 = blockIdx.x * 64, c0 = blockIdx.y * 64;
  const float* src = (bz < BN) ? x : y;
  u16* dst = (bz < BN) ? xT : yT;
  int b = bz & (BN - 1);
  src += (size_t)b * CD * ND;
  dst += (size_t)b * ND * CD;
#pragma unroll
  for (int it = 0; it < 4; ++it) {
    int idx = it * 256 + t;
    int ci = idx >> 4;
    int nj = (idx & 15) * 4;
    float4 v = *(const float4*)(src + (size_t)(c0 + ci) * ND + n0 + nj);
    tile[nj + 0][ci] = f2bf(v.x);
    tile[nj + 1][ci] = f2bf(v.y);
    tile[nj + 2][ci] = f2bf(v.z);
    tile[nj + 3][ci] = f2bf(v.w);
  }
  __syncthreads();
#pragma unroll
  for (int it = 0; it < 2; ++it) {
    int idx = it * 256 + t;
    int ni = idx >> 3;
    int cj = (idx & 7) * 8;
    uint4 v = *(const uint4*)&tile[ni][cj];
    *(uint4*)(dst + (size_t)(n0 + ni) * CD + c0 + cj) = v;
  }
}

// ---------- projection GEMM (bf16 in/out, fp32 bias) — round-5 structure ----
// C[m][n] = sum_k A[m][k]*Bw[n][k] + bias
// biasA for z==0, biasB for z>=1; bias_per_row selects axis
__global__ __launch_bounds__(256, 2) void k_proj(
    const u16* __restrict__ A, const u16* __restrict__ Bw,
    const float* __restrict__ biasA, const float* __restrict__ biasB,
    u16* __restrict__ C, int ldc, int bias_per_row,
    size_t aBS, size_t bBS, size_t cBS) {
  __shared__ alignas(16) u16 As[64][264];
  __shared__ alignas(16) u16 Bs[64][136];
  int m0 = blockIdx.x * 64, n0 = blockIdx.y * 64;
  size_t z = blockIdx.z;
  const float* bias = (z == 0) ? biasA : biasB;
  A += z * aBS; Bw += z * bBS; C += z * cBS;
  int t = threadIdx.x, w = t >> 6, l = t & 63;
  int lane16 = l & 15, quad = l >> 4;
#pragma unroll
  for (int it = 0; it < 8; ++it) {
    int c = it * 256 + t;
    int r = c >> 5, co = (c & 31) * 8;
    *(uint4*)&As[r][co] = *(const uint4*)(A + (size_t)(m0 + r) * CD + co);
  }
  ffrag acc[4];
#pragma unroll
  for (int tt = 0; tt < 4; ++tt) acc[tt] = ffrag{0.f, 0.f, 0.f, 0.f};
#pragma unroll
  for (int half = 0; half < 2; ++half) {
    if (half) __syncthreads();
#pragma unroll
    for (int it = 0; it < 4; ++it) {
      int c = it * 256 + t;
      int r = c >> 4, co = (c & 15) * 8;
      *(uint4*)&Bs[r][co] =
          *(const uint4*)(Bw + (size_t)(n0 + r) * CD + half * 128 + co);
    }
    __syncthreads();
#pragma unroll
    for (int kc = 0; kc < 4; ++kc) {
      bfrag af = *(const bfrag*)&As[w * 16 + lane16][half * 128 + kc * 32 + quad * 8];
#pragma unroll
      for (int tt = 0; tt < 4; ++tt) {
        bfrag bfr = *(const bfrag*)&Bs[tt * 16 + lane16][kc * 32 + quad * 8];
        acc[tt] = __builtin_amdgcn_mfma_f32_16x16x32_bf16(af, bfr, acc[tt], 0, 0, 0);
      }
    }
  }
#pragma unroll
  for (int tt = 0; tt < 4; ++tt) {
    int col = n0 + tt * 16 + lane16;
    float bcol = bias_per_row ? 0.f : bias[col];
#pragma unroll
    for (int r = 0; r < 4; ++r) {
      int row = m0 + w * 16 + quad * 4 + r;
      float bb = bias_per_row ? bias[row] : bcol;
      C[(size_t)row * ldc + col] = f2bf(acc[tt][r] + bb);
    }
  }
}

// ---------- flash attention, split-K, async-DMA double-buffered ----------
// Q,K: [B*N][C]; Vt: [B][C][N]. 128 q-rows/block, 4 waves x 2 m-tiles.
// One __syncthreads per K-tile. XOR-swizzled unpadded LDS (global_load_lds).
union SmemU {
  struct {
    u16 Ks[2][NK][256];   // 32,768 B  chunk^=(row&7) swizzle
    u16 Vs[2][CD][NK];    // 32,768 B  chunk^=((d>>1)&3) swizzle
    u16 Ps[8][16][40];    // 10,240 B  wave-private P staging
  } a;                     // 75,776 B
  u16 ot[CD][136];         // 69,632 B  epilogue O^T staging
};

template <int NS>
__global__ __launch_bounds__(256, 2) void k_attn(
    const u16* __restrict__ Q, const u16* __restrict__ K,
    const u16* __restrict__ Vt, u16* __restrict__ O01,
    u16* __restrict__ O23, float* __restrict__ Lpart) {
  constexpr int NIT = ND / NS / NK;
  __shared__ alignas(16) SmemU sm;
  int b = blockIdx.y, q0 = blockIdx.x * 128, z = blockIdx.z;
  int t = threadIdx.x, w = t >> 6, l = t & 63;
  int lane16 = l & 15, quad = l >> 4;
  const float scale = 0.0625f;  // 256^-0.5

  // Q frags: A-layout rows q0 + (w*2+mi)*16 + lane16
  bfrag qf[2][8];
#pragma unroll
  for (int mi = 0; mi < 2; ++mi) {
    const u16* Qrow =
        Q + ((size_t)b * ND + q0 + (w * 2 + mi) * 16 + lane16) * CD;
#pragma unroll
    for (int kc = 0; kc < 8; ++kc)
      qf[mi][kc] = *(const bfrag*)(Qrow + kc * 32 + quad * 8);
  }

  ffrag o[2][16];
#pragma unroll
  for (int mi = 0; mi < 2; ++mi)
#pragma unroll
    for (int i = 0; i < 16; ++i) o[mi][i] = ffrag{0.f, 0.f, 0.f, 0.f};
  float lsum[2][4] = {{0.f, 0.f, 0.f, 0.f}, {0.f, 0.f, 0.f, 0.f}};

  const u16* Kb = K + ((size_t)b * ND + z * (ND / NS)) * CD;
  const u16* Vb = Vt + (size_t)b * CD * ND + z * (ND / NS);

  auto stage = [&](int kt2) {
    int dbuf = kt2 & 1;
    const u16* Kt = Kb + (size_t)kt2 * NK * CD;
    const u16* Vtt = Vb + kt2 * NK;
#pragma unroll
    for (int p = 0; p < 4; ++p) {
      int r = p * 8 + w * 2 + (l >> 5);
      int j = (l & 31) ^ (r & 7);
      gload_lds(Kt + (size_t)r * CD + j * 8, &sm.a.Ks[dbuf][p * 8 + w * 2][0]);
    }
#pragma unroll
    for (int p = 0; p < 4; ++p) {
      int dd = p * 64 + w * 16 + (l >> 2);
      int j = (l & 3) ^ ((dd >> 1) & 3);
      gload_lds(Vtt + (size_t)dd * ND + j * 8, &sm.a.Vs[dbuf][p * 64 + w * 16][0]);
    }
  };

  stage(0);
  for (int kt = 0; kt < NIT; ++kt) {
    int dbuf = kt & 1;
    __syncthreads();  // drains DMA for buf dbuf; recycling of dbuf^1 is safe
    if (kt + 1 < NIT) stage(kt + 1);  // async into other buffer, no wait

    // S = Q K^T  (2 m-tiles x 2 key-tiles)
    ffrag s2[2][2];
#pragma unroll
    for (int mi = 0; mi < 2; ++mi)
#pragma unroll
      for (int tt = 0; tt < 2; ++tt) s2[mi][tt] = ffrag{0.f, 0.f, 0.f, 0.f};
#pragma unroll
    for (int kc = 0; kc < 8; ++kc) {
      bfrag kf0, kf1;
      {
        int r = lane16;
        int cp = (kc * 4 + quad) ^ (r & 7);
        kf0 = *(const bfrag*)&sm.a.Ks[dbuf][r][cp * 8];
        int r1 = 16 + lane16;
        int cp1 = (kc * 4 + quad) ^ (r1 & 7);
        kf1 = *(const bfrag*)&sm.a.Ks[dbuf][r1][cp1 * 8];
      }
#pragma unroll
      for (int mi = 0; mi < 2; ++mi) {
        s2[mi][0] = __builtin_amdgcn_mfma_f32_16x16x32_bf16(qf[mi][kc], kf0,
                                                            s2[mi][0], 0, 0, 0);
        s2[mi][1] = __builtin_amdgcn_mfma_f32_16x16x32_bf16(qf[mi][kc], kf1,
                                                            s2[mi][1], 0, 0, 0);
      }
    }

    // fixed-max softmax: p = exp(s*scale); lane-partial sums; P -> LDS
#pragma unroll
    for (int mi = 0; mi < 2; ++mi)
#pragma unroll
      for (int tt = 0; tt < 2; ++tt)
#pragma unroll
        for (int r = 0; r < 4; ++r) {
          float p = __expf(s2[mi][tt][r] * scale);
          lsum[mi][r] += p;
          sm.a.Ps[w * 2 + mi][quad * 4 + r][tt * 16 + lane16] = f2bf(p);
        }
    // wave-private Ps: in-wave LDS ordering suffices, no barrier
    bfrag pf0 = *(const bfrag*)&sm.a.Ps[w * 2 + 0][lane16][quad * 8];
    bfrag pf1 = *(const bfrag*)&sm.a.Ps[w * 2 + 1][lane16][quad * 8];

    // O += P V  (16 d-tiles, V-frag shared across both m-tiles)
#pragma unroll
    for (int dt = 0; dt < 16; ++dt) {
      int dd = dt * 16 + lane16;
      int cp = quad ^ ((dd >> 1) & 3);
      bfrag vf = *(const bfrag*)&sm.a.Vs[dbuf][dd][cp * 8];
      o[0][dt] = __builtin_amdgcn_mfma_f32_16x16x32_bf16(pf0, vf, o[0][dt], 0, 0, 0);
      o[1][dt] = __builtin_amdgcn_mfma_f32_16x16x32_bf16(pf1, vf, o[1][dt], 0, 0, 0);
    }
  }

  // row-sum reduction: 16-lane butterfly within quad groups, once
#pragma unroll
  for (int mi = 0; mi < 2; ++mi)
#pragma unroll
    for (int r = 0; r < 4; ++r) {
#pragma unroll
      for (int off = 1; off < 16; off <<= 1)
        lsum[mi][r] += __shfl_xor(lsum[mi][r], off, 64);
    }
  if (lane16 == 0) {
#pragma unroll
    for (int mi = 0; mi < 2; ++mi)
#pragma unroll
      for (int r = 0; r < 4; ++r)
        Lpart[((size_t)z * BN + b) * ND + q0 + (w * 2 + mi) * 16 + quad * 4 + r] =
            lsum[mi][r];
  }

  __syncthreads();
  // unnormalized O -> transposed bf16 staging ot[d][q_local]
#pragma unroll
  for (int mi = 0; mi < 2; ++mi)
#pragma unroll
    for (int dt = 0; dt < 16; ++dt)
#pragma unroll
      for (int r = 0; r < 4; ++r)
        sm.ot[dt * 16 + lane16][(w * 2 + mi) * 16 + quad * 4 + r] =
            f2bf(o[mi][dt][r]);
  __syncthreads();
  const size_t SZc = (size_t)BN * ND * CD;
  u16* Op = ((z < 2) ? O01 : O23) + (size_t)(z & 1) * SZc;
#pragma unroll
  for (int it = 0; it < 16; ++it) {
    int c = it * 256 + t;
    int dd = c >> 4, co = (c & 15) * 8;
    size_t g = ((size_t)b * CD + dd) * ND + q0 + co;
    *(uint4*)(Op + g) = *(const uint4*)&sm.ot[dd][co];
  }
}

// ---------- combine partials + residual ----------
template <int NS>
__global__ __launch_bounds__(256) void k_combine(
    const u16* __restrict__ O01, const u16* __restrict__ O23,
    const float* __restrict__ L, const float* __restrict__ x,
    float* __restrict__ out) {
  const size_t SZc = (size_t)BN * ND * CD;
  size_t e = ((size_t)blockIdx.x * 256 + threadIdx.x) * 8;
  int n = (int)(e & (ND - 1));
  int b = (int)(e >> 20);  // C*N = 2^20
  float ls[8] = {0, 0, 0, 0, 0, 0, 0, 0};
  float acc[8] = {0, 0, 0, 0, 0, 0, 0, 0};
#pragma unroll
  for (int z = 0; z < NS; ++z) {
    const float* Lr = L + ((size_t)z * BN + b) * ND + n;
    float4 l0 = *(const float4*)(Lr);
    float4 l1 = *(const float4*)(Lr + 4);
    ls[0] += l0.x; ls[1] += l0.y; ls[2] += l0.z; ls[3] += l0.w;
    ls[4] += l1.x; ls[5] += l1.y; ls[6] += l1.z; ls[7] += l1.w;
    const u16* Oz = ((z < 2) ? O01 : O23) + (size_t)(z & 1) * SZc + e;
    union { uint4 q; u16 s[8]; } u;
    u.q = *(const uint4*)Oz;
#pragma unroll
    for (int j = 0; j < 8; ++j) acc[j] += bf2f(u.s[j]);
  }
  float4 x0 = *(const float4*)(x + e);
  float4 x1 = *(const float4*)(x + e + 4);
  float4 r0, r1;
  r0.x = x0.x + acc[0] / ls[0];
  r0.y = x0.y + acc[1] / ls[1];
  r0.z = x0.z + acc[2] / ls[2];
  r0.w = x0.w + acc[3] / ls[3];
  r1.x = x1.x + acc[4] / ls[4];
  r1.y = x1.y + acc[5] / ls[5];
  r1.z = x1.z + acc[6] / ls[6];
  r1.w = x1.w + acc[7] / ls[7];
  *(float4*)(out + e) = r0;
  *(float4*)(out + e + 4) = r1;
}

extern "C" void kernel_launch(void* const* d_in, const int* in_sizes, int n_in,
                              void* d_out, int out_size, void* d_ws, size_t ws_size,
                              hipStream_t stream) {
  const float* x  = (const float*)d_in[0];
  const float* y  = (const float*)d_in[1];
  const float* Wq = (const float*)d_in[2];
  const float* bq = (const float*)d_in[3];
  const float* Wk = (const float*)d_in[4];
  const float* bk = (const float*)d_in[5];
  const float* Wv = (const float*)d_in[6];
  const float* bv = (const float*)d_in[7];
  float* out = (float*)d_out;
  u16* ws = (u16*)d_ws;
  const size_t SZ = (size_t)BN * ND * CD;  // 4,194,304 elems per tensor
  u16* xT = ws;            // [B][N][C]  -> reused as O01 (2 partials)
  u16* yT = xT + SZ;
  u16* Qb = yT + SZ;
  u16* Kb = Qb + SZ;
  u16* Vb = Kb + SZ;
  u16* O23 = Vb + SZ;      // 2 partials (NS=4), 2*SZ
  u16* wB = O23;           // bf16 weights overlay O23 (dead until k_attn)
  u16* O01 = xT;           // overlays dead xT,yT after projections
  // NS=4: 7*SZ bf16 + 4*BN*ND fp32 L = 59.0 MB
  const size_t need4 = 7 * SZ * sizeof(u16) + (size_t)4 * BN * ND * sizeof(float);
  const bool big = ws_size >= need4;  // constant across calls (graph-safe)
  const int cgrid = (int)(SZ / (256 * 8));  // 2048 blocks (out = SZ floats)

  // transposes + weight cast (z==8 slice)
  k_transpose<<<dim3(ND / 64, CD / 64, 9), 256, 0, stream>>>(
      x, y, Wq, Wk, Wv, xT, yT, wB);
  // merged Q+K projection: z=0 -> (xT, Wq, bq, Qb); z=1 -> (yT, Wk, bk, Kb)
  k_proj<<<dim3(BN * ND / 64, CD / 64, 2), 256, 0, stream>>>(
      xT, wB, bq, bk, Qb, CD, 0, SZ, (size_t)CD * CD, SZ);
  // V projection (transposed output): Vt[b][d][n]
  k_proj<<<dim3(CD / 64, ND / 64, BN), 256, 0, stream>>>(
      wB + (size_t)2 * CD * CD, yT, bv, bv, Vb, ND, 1,
      (size_t)0, (size_t)ND * CD, (size_t)CD * ND);
  if (big) {
    float* Lp = (float*)(O23 + 2 * SZ);
    k_attn<4><<<dim3(ND / 128, BN, 4), 256, 0, stream>>>(Qb, Kb, Vb, O01, O23, Lp);
    k_combine<4><<<dim3(cgrid), 256, 0, stream>>>(O01, O23, Lp, x, out);
  } else {
    float* Lp = (float*)(Vb + SZ);
    k_attn<2><<<dim3(ND / 128, BN, 2), 256, 0, stream>>>(Qb, Kb, Vb, O01, O01, Lp);
    k_combine<2><<<dim3(cgrid), 256, 0, stream>>>(O01, O01, Lp, x, out);
  }
}

// Round 10
// 199.800 us; speedup vs baseline: 1.1620x; 1.0354x over previous
//
#include <hip/hip_runtime.h>
#include <stdint.h>

#define BN 4
#define CD 256
#define ND 4096
#define NK 32            // key-tile size in attention

typedef unsigned short u16;
typedef short bfrag __attribute__((ext_vector_type(8)));  // 8 bf16 = 4 VGPR
typedef float ffrag __attribute__((ext_vector_type(4)));  // MFMA C/D frag

__device__ __forceinline__ float bf2f(u16 u) {
  union { unsigned int i; float f; } v;
  v.i = ((unsigned int)u) << 16;
  return v.f;
}
__device__ __forceinline__ u16 f2bf(float f) {
  union { float f; unsigned int i; } v;
  v.f = f;
  return (u16)((v.i + 0x7FFFu + ((v.i >> 16) & 1u)) >> 16);  // RNE
}
// async global->LDS DMA, 16B per lane; LDS dest = wave-uniform base + lane*16
__device__ __forceinline__ void gload_lds(const u16* g, u16* l) {
  __builtin_amdgcn_global_load_lds(
      (const __attribute__((address_space(1))) void*)g,
      (__attribute__((address_space(3))) void*)l, 16, 0, 0);
}

// ---------- Q/K projection, direct from fp32, one block = 64 rows x 256 d --
// grid (256, 2): x = m-tile (64 rows of B*N), y = 0:Q 1:K.
// Input tile transposed+cast to LDS ONCE (r7-verified pattern); weights
// chunk-staged to LDS with inline fp32->bf16 cast (4 chunks of 64 d).
__global__ __launch_bounds__(256, 2) void k_projQK(
    const float* __restrict__ x, const float* __restrict__ y,
    const float* __restrict__ Wq, const float* __restrict__ Wk,
    const float* __restrict__ bq, const float* __restrict__ bk,
    u16* __restrict__ Qb, u16* __restrict__ Kb) {
  __shared__ alignas(16) u16 As[64][264];  // As[n][c], input^T cast
  __shared__ alignas(16) u16 Ws[64][264];  // weight chunk [d_local][c]
  int m0 = blockIdx.x * 64;
  int z = blockIdx.y;
  int b = m0 >> 12, nsp = m0 & 4095;
  const float* src = (z ? y : x) + (size_t)b * CD * ND;
  const float* Wf = z ? Wk : Wq;
  const float* bias = z ? bk : bq;
  u16* Cd = (z ? Kb : Qb) + (size_t)m0 * CD;
  int t = threadIdx.x, w = t >> 6, l = t & 63;
  int lane16 = l & 15, quad = l >> 4;

  // A: As[nl][c] = src[c][nsp+nl], all 256 c (transpose+cast in LDS, once)
#pragma unroll
  for (int it = 0; it < 16; ++it) {
    int idx = it * 256 + t;
    int c = idx >> 4, nj = (idx & 15) * 4;
    float4 v = *(const float4*)(src + (size_t)c * ND + nsp + nj);
    As[nj + 0][c] = f2bf(v.x);
    As[nj + 1][c] = f2bf(v.y);
    As[nj + 2][c] = f2bf(v.z);
    As[nj + 3][c] = f2bf(v.w);
  }
  __syncthreads();

  // A-frags in registers (rows w*16+lane16)
  bfrag af[8];
#pragma unroll
  for (int kc = 0; kc < 8; ++kc)
    af[kc] = *(const bfrag*)&As[w * 16 + lane16][kc * 32 + quad * 8];

  ffrag acc[16];
#pragma unroll
  for (int i = 0; i < 16; ++i) acc[i] = ffrag{0.f, 0.f, 0.f, 0.f};

#pragma unroll
  for (int c4 = 0; c4 < 4; ++c4) {  // 4 chunks of 64 d
    if (c4) __syncthreads();        // prior MFMA done reading Ws
    // stage W rows c4*64..+63, inline cast (coalesced 1KB/wave loads)
#pragma unroll
    for (int it = 0; it < 16; ++it) {
      int idx = it * 256 + t;
      int row = idx >> 6, col = (idx & 63) * 4;
      float4 v = *(const float4*)(Wf + (size_t)(c4 * 64 + row) * CD + col);
      ushort4 o;
      o.x = f2bf(v.x); o.y = f2bf(v.y); o.z = f2bf(v.z); o.w = f2bf(v.w);
      *(ushort4*)&Ws[row][col] = o;
    }
    __syncthreads();
#pragma unroll
    for (int kc = 0; kc < 8; ++kc)
#pragma unroll
      for (int tt = 0; tt < 4; ++tt) {
        bfrag bfr = *(const bfrag*)&Ws[tt * 16 + lane16][kc * 32 + quad * 8];
        acc[c4 * 4 + tt] =
            __builtin_amdgcn_mfma_f32_16x16x32_bf16(af[kc], bfr, acc[c4 * 4 + tt], 0, 0, 0);
      }
  }
  // epilogue (r8-verified): row = w*16+quad*4+r, col = nt*16+lane16
#pragma unroll
  for (int nt = 0; nt < 16; ++nt) {
    int col = nt * 16 + lane16;
    float bcol = bias[col];
#pragma unroll
    for (int r = 0; r < 4; ++r) {
      int rowL = w * 16 + quad * 4 + r;
      Cd[(size_t)rowL * CD + col] = f2bf(acc[nt][r] + bcol);
    }
  }
}

// ---------- V projection, direct from fp32, out Vt[b][d][n] ----------
// grid (64, 4): x = n-tile, y = b. y^T tile staged ONCE; Wv chunk-staged.
__global__ __launch_bounds__(256, 2) void k_projV(
    const float* __restrict__ y, const float* __restrict__ Wv,
    const float* __restrict__ bv, u16* __restrict__ Vb) {
  __shared__ alignas(16) u16 Bs[64][264];  // Bs[n][c] = y^T cast
  __shared__ alignas(16) u16 Ws[64][264];  // Wv chunk [d_local][c]
  int n0s = blockIdx.x * 64;
  int b = blockIdx.y;
  const float* src = y + (size_t)b * CD * ND;
  u16* Cd = Vb + (size_t)b * CD * ND;
  int t = threadIdx.x, w = t >> 6, l = t & 63;
  int lane16 = l & 15, quad = l >> 4;

  // stage Bs[nl][c] = src[c][n0s+nl], all 256 c (once)
#pragma unroll
  for (int it = 0; it < 16; ++it) {
    int idx = it * 256 + t;
    int c = idx >> 4, nj = (idx & 15) * 4;
    float4 v = *(const float4*)(src + (size_t)c * ND + n0s + nj);
    Bs[nj + 0][c] = f2bf(v.x);
    Bs[nj + 1][c] = f2bf(v.y);
    Bs[nj + 2][c] = f2bf(v.z);
    Bs[nj + 3][c] = f2bf(v.w);
  }
  __syncthreads();

  // B-frags in registers (n rows w*16+lane16)
  bfrag bfr8[8];
#pragma unroll
  for (int kc = 0; kc < 8; ++kc)
    bfr8[kc] = *(const bfrag*)&Bs[w * 16 + lane16][kc * 32 + quad * 8];

  ffrag o[16];
#pragma unroll
  for (int i = 0; i < 16; ++i) o[i] = ffrag{0.f, 0.f, 0.f, 0.f};

#pragma unroll
  for (int c4 = 0; c4 < 4; ++c4) {  // 4 chunks of 64 d
    if (c4) __syncthreads();
#pragma unroll
    for (int it = 0; it < 16; ++it) {
      int idx = it * 256 + t;
      int row = idx >> 6, col = (idx & 63) * 4;
      float4 v = *(const float4*)(Wv + (size_t)(c4 * 64 + row) * CD + col);
      ushort4 ov;
      ov.x = f2bf(v.x); ov.y = f2bf(v.y); ov.z = f2bf(v.z); ov.w = f2bf(v.w);
      *(ushort4*)&Ws[row][col] = ov;
    }
    __syncthreads();
#pragma unroll
    for (int kc = 0; kc < 8; ++kc)
#pragma unroll
      for (int mt = 0; mt < 4; ++mt) {
        bfrag af = *(const bfrag*)&Ws[mt * 16 + lane16][kc * 32 + quad * 8];
        o[c4 * 4 + mt] =
            __builtin_amdgcn_mfma_f32_16x16x32_bf16(af, bfr8[kc], o[c4 * 4 + mt], 0, 0, 0);
      }
  }
  // epilogue (r8-verified mapping): d = c4*64 + mt*16 + quad*4 + r
#pragma unroll
  for (int i = 0; i < 16; ++i) {
    int c4 = i >> 2, mt = i & 3;
#pragma unroll
    for (int r = 0; r < 4; ++r) {
      int d = c4 * 64 + mt * 16 + quad * 4 + r;
      Cd[(size_t)d * ND + n0s + w * 16 + lane16] = f2bf(o[i][r] + bv[d]);
    }
  }
}

// ---------- flash attention, split-K, async-DMA double-buffered ----------
// Q,K: [B*N][C]; Vt: [B][C][N]. 128 q-rows/block, 4 waves x 2 m-tiles.
// One __syncthreads per K-tile. XOR-swizzled unpadded LDS (global_load_lds).
union SmemU {
  struct {
    u16 Ks[2][NK][256];   // 32,768 B  chunk^=(row&7) swizzle
    u16 Vs[2][CD][NK];    // 32,768 B  chunk^=((d>>1)&3) swizzle
    u16 Ps[8][16][40];    // 10,240 B  wave-private P staging
  } a;                     // 75,776 B
  u16 ot[CD][136];         // 69,632 B  epilogue O^T staging
};

template <int NS>
__global__ __launch_bounds__(256, 2) void k_attn(
    const u16* __restrict__ Q, const u16* __restrict__ K,
    const u16* __restrict__ Vt, u16* __restrict__ O01,
    u16* __restrict__ O23, float* __restrict__ Lpart) {
  constexpr int NIT = ND / NS / NK;
  __shared__ alignas(16) SmemU sm;
  int b = blockIdx.y, q0 = blockIdx.x * 128, z = blockIdx.z;
  int t = threadIdx.x, w = t >> 6, l = t & 63;
  int lane16 = l & 15, quad = l >> 4;
  const float scale = 0.0625f;  // 256^-0.5

  // Q frags: A-layout rows q0 + (w*2+mi)*16 + lane16
  bfrag qf[2][8];
#pragma unroll
  for (int mi = 0; mi < 2; ++mi) {
    const u16* Qrow =
        Q + ((size_t)b * ND + q0 + (w * 2 + mi) * 16 + lane16) * CD;
#pragma unroll
    for (int kc = 0; kc < 8; ++kc)
      qf[mi][kc] = *(const bfrag*)(Qrow + kc * 32 + quad * 8);
  }

  ffrag o[2][16];
#pragma unroll
  for (int mi = 0; mi < 2; ++mi)
#pragma unroll
    for (int i = 0; i < 16; ++i) o[mi][i] = ffrag{0.f, 0.f, 0.f, 0.f};
  float lsum[2][4] = {{0.f, 0.f, 0.f, 0.f}, {0.f, 0.f, 0.f, 0.f}};

  const u16* Kb = K + ((size_t)b * ND + z * (ND / NS)) * CD;
  const u16* Vb = Vt + (size_t)b * CD * ND + z * (ND / NS);

  auto stage = [&](int kt2) {
    int dbuf = kt2 & 1;
    const u16* Kt = Kb + (size_t)kt2 * NK * CD;
    const u16* Vtt = Vb + kt2 * NK;
#pragma unroll
    for (int p = 0; p < 4; ++p) {
      int r = p * 8 + w * 2 + (l >> 5);
      int j = (l & 31) ^ (r & 7);
      gload_lds(Kt + (size_t)r * CD + j * 8, &sm.a.Ks[dbuf][p * 8 + w * 2][0]);
    }
#pragma unroll
    for (int p = 0; p < 4; ++p) {
      int dd = p * 64 + w * 16 + (l >> 2);
      int j = (l & 3) ^ ((dd >> 1) & 3);
      gload_lds(Vtt + (size_t)dd * ND + j * 8, &sm.a.Vs[dbuf][p * 64 + w * 16][0]);
    }
  };

  stage(0);
  for (int kt = 0; kt < NIT; ++kt) {
    int dbuf = kt & 1;
    __syncthreads();  // drains DMA for buf dbuf; recycling of dbuf^1 is safe
    if (kt + 1 < NIT) stage(kt + 1);  // async into other buffer, no wait

    // S = Q K^T  (2 m-tiles x 2 key-tiles)
    ffrag s2[2][2];
#pragma unroll
    for (int mi = 0; mi < 2; ++mi)
#pragma unroll
      for (int tt = 0; tt < 2; ++tt) s2[mi][tt] = ffrag{0.f, 0.f, 0.f, 0.f};
#pragma unroll
    for (int kc = 0; kc < 8; ++kc) {
      bfrag kf0, kf1;
      {
        int r = lane16;
        int cp = (kc * 4 + quad) ^ (r & 7);
        kf0 = *(const bfrag*)&sm.a.Ks[dbuf][r][cp * 8];
        int r1 = 16 + lane16;
        int cp1 = (kc * 4 + quad) ^ (r1 & 7);
        kf1 = *(const bfrag*)&sm.a.Ks[dbuf][r1][cp1 * 8];
      }
#pragma unroll
      for (int mi = 0; mi < 2; ++mi) {
        s2[mi][0] = __builtin_amdgcn_mfma_f32_16x16x32_bf16(qf[mi][kc], kf0,
                                                            s2[mi][0], 0, 0, 0);
        s2[mi][1] = __builtin_amdgcn_mfma_f32_16x16x32_bf16(qf[mi][kc], kf1,
                                                            s2[mi][1], 0, 0, 0);
      }
    }

    // fixed-max softmax: p = exp(s*scale); lane-partial sums; P -> LDS
#pragma unroll
    for (int mi = 0; mi < 2; ++mi)
#pragma unroll
      for (int tt = 0; tt < 2; ++tt)
#pragma unroll
        for (int r = 0; r < 4; ++r) {
          float p = __expf(s2[mi][tt][r] * scale);
          lsum[mi][r] += p;
          sm.a.Ps[w * 2 + mi][quad * 4 + r][tt * 16 + lane16] = f2bf(p);
        }
    // wave-private Ps: in-wave LDS ordering suffices, no barrier
    bfrag pf0 = *(const bfrag*)&sm.a.Ps[w * 2 + 0][lane16][quad * 8];
    bfrag pf1 = *(const bfrag*)&sm.a.Ps[w * 2 + 1][lane16][quad * 8];

    // O += P V  (16 d-tiles, V-frag shared across both m-tiles)
#pragma unroll
    for (int dt = 0; dt < 16; ++dt) {
      int dd = dt * 16 + lane16;
      int cp = quad ^ ((dd >> 1) & 3);
      bfrag vf = *(const bfrag*)&sm.a.Vs[dbuf][dd][cp * 8];
      o[0][dt] = __builtin_amdgcn_mfma_f32_16x16x32_bf16(pf0, vf, o[0][dt], 0, 0, 0);
      o[1][dt] = __builtin_amdgcn_mfma_f32_16x16x32_bf16(pf1, vf, o[1][dt], 0, 0, 0);
    }
  }

  // row-sum reduction: 16-lane butterfly within quad groups, once
#pragma unroll
  for (int mi = 0; mi < 2; ++mi)
#pragma unroll
    for (int r = 0; r < 4; ++r) {
#pragma unroll
      for (int off = 1; off < 16; off <<= 1)
        lsum[mi][r] += __shfl_xor(lsum[mi][r], off, 64);
    }
  if (lane16 == 0) {
#pragma unroll
    for (int mi = 0; mi < 2; ++mi)
#pragma unroll
      for (int r = 0; r < 4; ++r)
        Lpart[((size_t)z * BN + b) * ND + q0 + (w * 2 + mi) * 16 + quad * 4 + r] =
            lsum[mi][r];
  }

  __syncthreads();
  // unnormalized O -> transposed bf16 staging ot[d][q_local]
#pragma unroll
  for (int mi = 0; mi < 2; ++mi)
#pragma unroll
    for (int dt = 0; dt < 16; ++dt)
#pragma unroll
      for (int r = 0; r < 4; ++r)
        sm.ot[dt * 16 + lane16][(w * 2 + mi) * 16 + quad * 4 + r] =
            f2bf(o[mi][dt][r]);
  __syncthreads();
  const size_t SZc = (size_t)BN * ND * CD;
  u16* Op = ((z < 2) ? O01 : O23) + (size_t)(z & 1) * SZc;
#pragma unroll
  for (int it = 0; it < 16; ++it) {
    int c = it * 256 + t;
    int dd = c >> 4, co = (c & 15) * 8;
    size_t g = ((size_t)b * CD + dd) * ND + q0 + co;
    *(uint4*)(Op + g) = *(const uint4*)&sm.ot[dd][co];
  }
}

// ---------- combine partials + residual ----------
template <int NS>
__global__ __launch_bounds__(256) void k_combine(
    const u16* __restrict__ O01, const u16* __restrict__ O23,
    const float* __restrict__ L, const float* __restrict__ x,
    float* __restrict__ out) {
  const size_t SZc = (size_t)BN * ND * CD;
  size_t e = ((size_t)blockIdx.x * 256 + threadIdx.x) * 8;
  int n = (int)(e & (ND - 1));
  int b = (int)(e >> 20);  // C*N = 2^20
  float ls[8] = {0, 0, 0, 0, 0, 0, 0, 0};
  float acc[8] = {0, 0, 0, 0, 0, 0, 0, 0};
#pragma unroll
  for (int z = 0; z < NS; ++z) {
    const float* Lr = L + ((size_t)z * BN + b) * ND + n;
    float4 l0 = *(const float4*)(Lr);
    float4 l1 = *(const float4*)(Lr + 4);
    ls[0] += l0.x; ls[1] += l0.y; ls[2] += l0.z; ls[3] += l0.w;
    ls[4] += l1.x; ls[5] += l1.y; ls[6] += l1.z; ls[7] += l1.w;
    const u16* Oz = ((z < 2) ? O01 : O23) + (size_t)(z & 1) * SZc + e;
    union { uint4 q; u16 s[8]; } u;
    u.q = *(const uint4*)Oz;
#pragma unroll
    for (int j = 0; j < 8; ++j) acc[j] += bf2f(u.s[j]);
  }
  float4 x0 = *(const float4*)(x + e);
  float4 x1 = *(const float4*)(x + e + 4);
  float4 r0, r1;
  r0.x = x0.x + acc[0] / ls[0];
  r0.y = x0.y + acc[1] / ls[1];
  r0.z = x0.z + acc[2] / ls[2];
  r0.w = x0.w + acc[3] / ls[3];
  r1.x = x1.x + acc[4] / ls[4];
  r1.y = x1.y + acc[5] / ls[5];
  r1.z = x1.z + acc[6] / ls[6];
  r1.w = x1.w + acc[7] / ls[7];
  *(float4*)(out + e) = r0;
  *(float4*)(out + e + 4) = r1;
}

extern "C" void kernel_launch(void* const* d_in, const int* in_sizes, int n_in,
                              void* d_out, int out_size, void* d_ws, size_t ws_size,
                              hipStream_t stream) {
  const float* x  = (const float*)d_in[0];
  const float* y  = (const float*)d_in[1];
  const float* Wq = (const float*)d_in[2];
  const float* bq = (const float*)d_in[3];
  const float* Wk = (const float*)d_in[4];
  const float* bk = (const float*)d_in[5];
  const float* Wv = (const float*)d_in[6];
  const float* bv = (const float*)d_in[7];
  float* out = (float*)d_out;
  u16* ws = (u16*)d_ws;
  const size_t SZ = (size_t)BN * ND * CD;  // 4,194,304 elems per tensor
  u16* Qb = ws;
  u16* Kb = Qb + SZ;
  u16* Vb = Kb + SZ;
  u16* Ob = Vb + SZ;  // NS partials, contiguous
  // NS=4: 7*SZ bf16 + 4*BN*ND fp32 = 58.7 MB + 256 KB
  const size_t need4 = 7 * SZ * sizeof(u16) + (size_t)4 * BN * ND * sizeof(float);
  const bool big = ws_size >= need4;  // constant across calls (graph-safe)
  const int cgrid = (int)(SZ / (256 * 8));  // 2048 blocks (out = SZ floats)

  k_projQK<<<dim3(256, 2), 256, 0, stream>>>(x, y, Wq, Wk, bq, bk, Qb, Kb);
  k_projV<<<dim3(64, 4), 256, 0, stream>>>(y, Wv, bv, Vb);
  if (big) {
    float* Lp = (float*)(Ob + 4 * SZ);
    k_attn<4><<<dim3(ND / 128, BN, 4), 256, 0, stream>>>(Qb, Kb, Vb, Ob,
                                                         Ob + 2 * SZ, Lp);
    k_combine<4><<<dim3(cgrid), 256, 0, stream>>>(Ob, Ob + 2 * SZ, Lp, x, out);
  } else {
    float* Lp = (float*)(Ob + 2 * SZ);
    k_attn<2><<<dim3(ND / 128, BN, 2), 256, 0, stream>>>(Qb, Kb, Vb, Ob, Ob, Lp);
    k_combine<2><<<dim3(cgrid), 256, 0, stream>>>(Ob, Ob, Lp, x, out);
  }
}